// Round 15
// baseline (176.920 us; speedup 1.0000x reference)
//
#include <hip/hip_runtime.h>
#include <hip/hip_bf16.h>

typedef unsigned short u16;
typedef unsigned int   u32;
typedef short   bf16x8 __attribute__((ext_vector_type(8)));  // bf16 carried as i16
typedef float   f32x4  __attribute__((ext_vector_type(4)));

__device__ __forceinline__ float bf2f(u16 u) {
    u32 t = ((u32)u) << 16;
    return __builtin_bit_cast(float, t);
}
__device__ __forceinline__ u32 f2bf(float f) {
    u32 u = __builtin_bit_cast(u32, f);
    return (u + 0x7FFFu + ((u >> 16) & 1u)) >> 16;   // RNE
}
// async global->LDS DMA, 16 B per lane (dst = wave-uniform base + lane*16)
__device__ __forceinline__ void load_lds16(const u16* g, u16* l) {
    __builtin_amdgcn_global_load_lds(
        (const __attribute__((address_space(1))) u32*)(const void*)g,
        (__attribute__((address_space(3))) u32*)(void*)l, 16, 0, 0);
}
// Inline-asm loads (saddr form): compiler cannot sink these or auto-wait on
// them -> true async issue, paired with manual vmcnt (rule #18).
// ALL loads 16B-aligned dwordx4 (no alignment hazards).
__device__ __forceinline__ uint4 gload4(const u16* sbase, u32 voff) {
    uint4 r;
    asm volatile("global_load_dwordx4 %0, %1, %2"
                 : "=v"(r) : "v"(voff), "s"(sbase) : "memory");
    return r;
}
__device__ __forceinline__ f32x4 gload4f(const float* sbase, u32 voff) {
    f32x4 r;
    asm volatile("global_load_dwordx4 %0, %1, %2"
                 : "=v"(r) : "v"(voff), "s"(sbase) : "memory");
    return r;
}
#define WAITVM(N) do { asm volatile("s_waitcnt vmcnt(" #N ")" ::: "memory"); \
                       __builtin_amdgcn_sched_barrier(0); } while (0)

// ---------------------------------------------------------------------------
// GLOBAL K-ORDER (both GEMMs): r = t*256 + c  (tap-major).
// XCD swizzle (verified r6): xcd = bid&7 -> 32-row band of one image.
// Channel-last xt[b][pixel][c] (r8). Divergence-aware gather lane maps
// (kfused r9/r10; koffg r14). koffg T4 raw-barrier (r12).
// kfused 2-blocks/CU (r13: 75 -> 62us).
// r15: koffg K-SPLIT — 512 thr, 8 waves, group kg = tid>>8 handles 18 of
// the 36 kt with its own LDS double-buffer (72 KB, still 2 blocks/CU ->
// 16 waves/CU). Wall barrier-rounds per block halve; groups run the same
// T4 loop in lockstep (equal barrier counts). Final cross-group f32 add.
// NOTE: K-fold order changes (two halves summed) — offsets shift ~1e-7,
// output absmax expected ~0.031-0.05 (threshold 0.0969).
// ---------------------------------------------------------------------------

// Kernel 0a: offset/mask conv weights -> hi/lo bf16 A[32][2304], r = t*256+c
__global__ void kprep(const float* __restrict__ woff, const float* __restrict__ wmod,
                      u16* __restrict__ ah, u16* __restrict__ al) {
    int i = blockIdx.x * 256 + threadIdx.x;      // 288 blocks -> 73728 exact
    if (i >= 32 * 2304) return;
    int oc = i / 2304, r = i - oc * 2304;
    int t = r >> 8, c = r & 255;
    float v = 0.f;
    if (oc < 18)      v = woff[oc * 2304 + c * 9 + t];
    else if (oc < 27) v = wmod[(oc - 18) * 2304 + c * 9 + t];
    u32 hb = f2bf(v);
    u32 lb = f2bf(v - bf2f((u16)hb));
    ah[i] = (u16)hb;
    al[i] = (u16)lb;
}

// Kernel 0b: w_reg f32 -> bf16, layout [o][t*256+c] (matches gather K-order).
__global__ void kwreg(const float* __restrict__ wreg, u16* __restrict__ wregb) {
    int i = blockIdx.x * 256 + threadIdx.x;      // 2304 blocks exact
    int o = i / 2304, r = i - o * 2304;
    int t = r >> 8, c = r & 255;
    wregb[i] = (u16)f2bf(wreg[o * 2304 + c * 9 + t]);
}

// Kernel 0c: transpose x[b][c][p] -> xt[b][p][c]  (channel-last, 16 MB).
__global__ __launch_bounds__(256) void ktrans(const float* __restrict__ x,
                                              float* __restrict__ xt) {
    __shared__ float T[64][65];
    int t = threadIdx.x;
    int pl = t & 63, cr = t >> 6;                // 4 rows per pass
    int p0 = blockIdx.x * 64;                    // pixel tile
    int c0 = blockIdx.y * 64;                    // channel tile
    int b  = blockIdx.z;
    const float* xb  = x  + ((long)b << 20);
    float*       xtb = xt + ((long)b << 20);
#pragma unroll
    for (int i = 0; i < 16; i++) {
        int c = cr + i * 4;
        T[c][pl] = xb[((long)(c0 + c) << 12) + p0 + pl];
    }
    __syncthreads();
#pragma unroll
    for (int i = 0; i < 16; i++) {
        int p = cr + i * 4;
        xtb[(long)(p0 + p) * 256 + c0 + pl] = T[pl][p];
    }
}

// ---------------------------------------------------------------------------
// Kernel 1: offset/mask conv as MFMA GEMM, M=32 (27 live), N=16384, K=2304.
// r15 K-split: 512 thr, 8 waves; group kg = tid>>8 runs the r12 T4 loop on
// kt = kg*18 .. kg*18+17 with private LDS double-buffer [kg*2+buf].
// Staging roles from ltid = tid&255 (identical per group); vmcnt is
// per-wave so each group's WAITVM sees only its own loads. 19 barriers per
// group (lockstep). Cross-group reduction via 4 KB retired LDS.
// ---------------------------------------------------------------------------
__global__ __launch_bounds__(512, 4) void koffg(const float* __restrict__ xt,
                                                const u16* __restrict__ ah_g,
                                                const u16* __restrict__ al_g,
                                                const float* __restrict__ boff,
                                                const float* __restrict__ bmod,
                                                float* __restrict__ offf) {
    __shared__ u16 Ah[4][32 * 72], Al[4][32 * 72]; // [kg*2+buf], 72 KB total
    __shared__ u16 Bh[4][32 * 72], Bl[4][32 * 72];
    int tid = threadIdx.x;
    int ltid = tid & 255, kg = tid >> 8;         // K-group 0/1
    // XCD swizzle: 512 blocks, xcd = bid&7 -> (img, band), j -> row/half
    int bid = blockIdx.x;
    int xcd = bid & 7, j = bid >> 3;             // j in [0,64)
    int img = xcd >> 1;
    int row = ((xcd & 1) << 5) + (j >> 1);
    int n0 = ((img << 6) + row) * 64 + (j & 1) * 32;
    int b = n0 >> 12, h0 = (n0 & 4095) >> 6, w0 = n0 & 63;
    int lane = tid & 63, wv = tid >> 6;          // wv 0..7
    int mt = wv & 1, nt = (wv >> 1) & 1;         // 2 m-tiles x 2 n-tiles of 16
    int col = lane & 15, quad = lane >> 4;

    int aoc = ltid >> 3, ak0 = (ltid & 7) * 8;   // A staging role (per group)
    int chq = lane & 15, pxs = lane >> 4;        // B staging: ch-quad, px-slot
    int px0 = (wv & 3) * 4 + pxs, px1 = px0 + 16;// own pixels (0..15, 16..31)

    int ktb = kg * 18;                           // group's first kt

    const float* xtb = xt + ((long)b << 20);     // image base (SGPR)
    u32 avoff0 = (u32)(aoc * 2304 + ak0) * 2;    // bytes into ah_g/al_g

    f32x4 acc = (f32x4){0.f, 0.f, 0.f, 0.f};

    uint4 pah, pal;
    f32x4 xa, xc;                                // px0 / px1 channel quads
    bool  vma, vmb;

    auto issue = [&](int kt) {                   // 4 asm loads, stay in flight
        int t = kt >> 2, c0 = (kt & 3) << 6, r0 = kt * 64;
        int dy = t / 3 - 1, dx = t % 3 - 1;
        pah = gload4(ah_g, avoff0 + (u32)r0 * 2);
        pal = gload4(al_g, avoff0 + (u32)r0 * 2);
        int hp = h0 + dy;
        bool vh = (unsigned)hp < 64u;
        int hc = min(max(hp, 0), 63);
        u32 cb = (u32)(c0 + chq * 4) << 2;       // channel byte offset (16B-al)
        int wpa = w0 + px0 + dx;
        vma = vh && ((unsigned)wpa < 64u);
        int wca = min(max(wpa, 0), 63);
        xa = gload4f(xtb, ((u32)(hc * 64 + wca) << 10) + cb);
        int wpb = w0 + px1 + dx;
        vmb = vh && ((unsigned)wpb < 64u);
        int wcb = min(max(wpb, 0), 63);
        xc = gload4f(xtb, ((u32)(hc * 64 + wcb) << 10) + cb);
    };
    auto stores = [&](int buf) {                 // after WAITVM(0); buf in {0,1}
        int sb = kg * 2 + buf;
        *(uint4*)&Ah[sb][aoc * 72 + ak0] = pah;
        *(uint4*)&Al[sb][aoc * 72 + ak0] = pal;
        u32 wh[2], wl[2];
#pragma unroll
        for (int i = 0; i < 4; i++) {
            float v = vma ? xa[i] : 0.f;
            u32 hb = f2bf(v);
            u32 lb = f2bf(v - bf2f((u16)hb));
            if (i & 1) { wh[i >> 1] |= hb << 16; wl[i >> 1] |= lb << 16; }
            else       { wh[i >> 1]  = hb;       wl[i >> 1]  = lb; }
        }
        *(uint2*)&Bh[sb][px0 * 72 + chq * 4] = make_uint2(wh[0], wh[1]);
        *(uint2*)&Bl[sb][px0 * 72 + chq * 4] = make_uint2(wl[0], wl[1]);
#pragma unroll
        for (int i = 0; i < 4; i++) {
            float v = vmb ? xc[i] : 0.f;
            u32 hb = f2bf(v);
            u32 lb = f2bf(v - bf2f((u16)hb));
            if (i & 1) { wh[i >> 1] |= hb << 16; wl[i >> 1] |= lb << 16; }
            else       { wh[i >> 1]  = hb;       wl[i >> 1]  = lb; }
        }
        *(uint2*)&Bh[sb][px1 * 72 + chq * 4] = make_uint2(wh[0], wh[1]);
        *(uint2*)&Bl[sb][px1 * 72 + chq * 4] = make_uint2(wl[0], wl[1]);
    };

    // prologue: group batch 0 loaded+stored; batch 1 issued (flies over barrier)
    issue(ktb + 0);
    WAITVM(0);
    stores(0);
    issue(ktb + 1);
    asm volatile("s_waitcnt lgkmcnt(0)" ::: "memory");
    __builtin_amdgcn_s_barrier();
    __builtin_amdgcn_sched_barrier(0);

    for (int kt = 0; kt < 18; kt++) {            // group-local kt
        int cur = kt & 1, nxt = kt + 1;
        int sb = kg * 2 + cur;
#pragma unroll
        for (int ks = 0; ks < 2; ks++) {
            int ko = ks * 32 + quad * 8;
            bf16x8 fah = *(const bf16x8*)&Ah[sb][(mt * 16 + col) * 72 + ko];
            bf16x8 fal = *(const bf16x8*)&Al[sb][(mt * 16 + col) * 72 + ko];
            bf16x8 fbh = *(const bf16x8*)&Bh[sb][(nt * 16 + col) * 72 + ko];
            bf16x8 fbl = *(const bf16x8*)&Bl[sb][(nt * 16 + col) * 72 + ko];
            acc = __builtin_amdgcn_mfma_f32_16x16x32_bf16(fah, fbh, acc, 0, 0, 0);
            acc = __builtin_amdgcn_mfma_f32_16x16x32_bf16(fah, fbl, acc, 0, 0, 0);
            acc = __builtin_amdgcn_mfma_f32_16x16x32_bf16(fal, fbh, acc, 0, 0, 0);
        }
        if (nxt < 18) {
            WAITVM(0);                           // group batch nxt arrived
            stores(nxt & 1);                     // ds_write own buf nxt&1
            if (nxt + 1 < 18) issue(ktb + nxt + 1);  // flies across barrier
        }
        asm volatile("s_waitcnt lgkmcnt(0)" ::: "memory");  // my ds_writes done
        __builtin_amdgcn_s_barrier();            // RAW barrier: no vmcnt drain
        __builtin_amdgcn_sched_barrier(0);
    }

    // cross-group reduction: kg1 publishes, kg0 adds (retired LDS, 4 KB)
    float* scratch = (float*)&Ah[0][0];
    if (kg) *(f32x4*)&scratch[ltid * 4] = acc;
    __syncthreads();
    if (kg == 0) {
        f32x4 o = *(const f32x4*)&scratch[ltid * 4];
        acc += o;
        int n = n0 + nt * 16 + col;
#pragma unroll
        for (int r = 0; r < 4; r++) {
            int oc = mt * 16 + quad * 4 + r;
            float s = acc[r];
            if (oc < 18) {
                int ch = 3 * (oc >> 1) + (oc & 1);   // even oc -> dy, odd -> dx
                offf[(ch << 14) + n] = s + boff[oc];
            } else if (oc < 27) {
                float tt = s + bmod[oc - 18];
                int ch = 3 * (oc - 18) + 2;
                offf[(ch << 14) + n] = 2.f / (1.f + __expf(-tt));
            }
        }
    }
}

// ---------------------------------------------------------------------------
// Kernel 2 (FUSED): sampling + GEMM + BN + ReLU.  r13-EXACT (verified
// ~62-64 us, occupancy 35%): 32 px/block, grid 512, 2 blocks/CU,
// divergence-aware gathers. Queued: Sl write bank-conflict swizzle.
// ---------------------------------------------------------------------------
__global__ __launch_bounds__(512, 4) void kfused(const float* __restrict__ xt,
                                                 const float* __restrict__ offf,
                                                 const u16* __restrict__ wregb,
                                                 const float* __restrict__ gamma,
                                                 const float* __restrict__ beta,
                                                 const float* __restrict__ rmean,
                                                 const float* __restrict__ rvar,
                                                 float* __restrict__ out) {
    __shared__ u16 Wl[2][256 * 64];  // [buf][o][k] granule-XOR-swizzled, 64 KB
    __shared__ u16 Sl[2][8 * 32 * 8];// [buf][c-octet][px][8ch], 8 KB
    int tid = threadIdx.x;
    int lane = tid & 63, wv = tid >> 6;
    int chq = lane & 15;                         // channel-quad 0..15
    int plo = wv * 4 + (lane >> 4);              // own pixel 0..31
    // XCD swizzle: 512 blocks, xcd = bid&7 -> (img, band), j -> row/half
    int bid = blockIdx.x;
    int xcd = bid & 7, jj = bid >> 3;            // jj in [0,64)
    int bb  = xcd >> 1;                          // image   (block-uniform)
    int h   = ((xcd & 1) << 5) + (jj >> 1);      // row     (block-uniform)
    int nbase = ((bb << 6) + h) * 64 + (jj & 1) * 32;  // first pixel (32/block)
    int wo = wv * 32;                            // wave output tile 32o x 32n
    int col = lane & 15, quad = lane >> 4;

    const float* xb = xt + ((long)bb << 20);     // image base (SGPR)

    f32x4 acc[2][2];
#pragma unroll
    for (int i = 0; i < 2; i++)
#pragma unroll
        for (int j = 0; j < 2; j++) acc[i][j] = (f32x4){0.f, 0.f, 0.f, 0.f};

    u32   pb[4];                                 // neighbor record byte offs
    float sw[4];                                 // bilinear*mask weights
    f32x4 g[4];                                  // in-flight 4ch quads

    auto tapcomp = [&](int t) {                  // own pixel's tap state
        int n = nbase + plo;
        int w = n & 63;
        int gy = t / 3, tx = t - 3 * gy;
        float dy = offf[((3 * t + 0) << 14) + n];
        float dx = offf[((3 * t + 1) << 14) + n];
        float m  = offf[((3 * t + 2) << 14) + n];
        float py = (float)(h - 1 + gy) + dy;
        float px = (float)(w - 1 + tx) + dx;
        float y0f = floorf(py), x0f = floorf(px);
        float wy = py - y0f, wx = px - x0f;
        int iy0 = (int)y0f, ix0 = (int)x0f;
        int iy1 = iy0 + 1, ix1 = ix0 + 1;
        bool vy0 = (unsigned)iy0 < 64u, vy1 = (unsigned)iy1 < 64u;
        bool vx0 = (unsigned)ix0 < 64u, vx1 = (unsigned)ix1 < 64u;
        int cy0 = min(max(iy0, 0), 63), cy1 = min(max(iy1, 0), 63);
        int cx0 = min(max(ix0, 0), 63), cx1 = min(max(ix1, 0), 63);
        pb[0] = (u32)(cy0 * 64 + cx0) << 10; pb[1] = (u32)(cy0 * 64 + cx1) << 10;
        pb[2] = (u32)(cy1 * 64 + cx0) << 10; pb[3] = (u32)(cy1 * 64 + cx1) << 10;
        float a = 1.f - wy, bw = 1.f - wx;
        sw[0] = (vy0 && vx0) ? a  * bw * m : 0.f;
        sw[1] = (vy0 && vx1) ? a  * wx * m : 0.f;
        sw[2] = (vy1 && vx0) ? wy * bw * m : 0.f;
        sw[3] = (vy1 && vx1) ? wy * wx * m : 0.f;
    };
    auto gissue = [&](int kt) {                  // 4 dwordx4 (one per neighbor)
        u32 co = ((u32)(kt & 3) << 8) + (u32)chq * 16;
#pragma unroll
        for (int nb = 0; nb < 4; nb++) g[nb] = gload4f(xb, pb[nb] + co);
    };
    auto dmaA = [&](int kt, int buf) {           // async A staging, 32 KB
#pragma unroll
        for (int i = 0; i < 4; i++) {
            int cidx = tid + i * 512;
            int o = cidx >> 3, qp = cidx & 7;
            int ql = qp ^ (o & 7);               // source-side XOR swizzle
            load_lds16(wregb + (long)o * 2304 + kt * 64 + ql * 8,
                       &Wl[buf][cidx * 8]);
        }
    };
    auto bwrite = [&](int buf) {                 // combine + pack + 8B write
        f32x4 v = sw[0] * g[0] + sw[1] * g[1] + sw[2] * g[2] + sw[3] * g[3];
        u32 w0 = f2bf(v[0]) | (f2bf(v[1]) << 16);
        u32 w1 = f2bf(v[2]) | (f2bf(v[3]) << 16);
        *(uint2*)&Sl[buf][((chq >> 1) * 32 + plo) * 8 + (chq & 1) * 4] =
            make_uint2(w0, w1);
    };

    // prologue: fill buffer 0
    tapcomp(0);
    gissue(0);
    dmaA(0, 0);
    WAITVM(0);
    bwrite(0);
    __syncthreads();

    for (int kt = 0; kt < 36; kt++) {
        int cur = kt & 1, nxt = kt + 1;
        if (nxt < 36) {
            if ((nxt & 3) == 0) tapcomp(nxt >> 2);
            gissue(nxt);                         // 4 oldest outstanding vmem
            dmaA(nxt, nxt & 1);                  // 4 newest (drain at barrier)
        }
#pragma unroll
        for (int ks = 0; ks < 2; ks++) {
            bf16x8 af[2], bfr[2];
#pragma unroll
            for (int i = 0; i < 2; i++) {
                int r = wo + i * 16 + col;
                int ph = (ks * 4 + quad) ^ (r & 7);
                af[i] = *(const bf16x8*)&Wl[cur][r * 64 + ph * 8];
            }
#pragma unroll
            for (int j = 0; j < 2; j++)
                bfr[j] = *(const bf16x8*)&Sl[cur][((ks * 4 + quad) * 32 +
                                                   (j * 16 + col)) * 8];
#pragma unroll
            for (int i = 0; i < 2; i++)
#pragma unroll
                for (int j = 0; j < 2; j++)
                    acc[i][j] = __builtin_amdgcn_mfma_f32_16x16x32_bf16(
                        af[i], bfr[j], acc[i][j], 0, 0, 0);
        }
        if (nxt < 36) {
            WAITVM(4);                           // gathers done, DMA may fly
            bwrite(nxt & 1);
        }
        __syncthreads();                         // drains DMA + ds_write; one/kt
    }

    // epilogue: BN + ReLU, D layout: row(o) = quad*4+reg, col(n) = lane&15
#pragma unroll
    for (int i = 0; i < 2; i++) {
        int ob = wo + i * 16 + quad * 4;
        float inv[4], add[4];
#pragma unroll
        for (int r = 0; r < 4; r++) {
            int o = ob + r;
            float iv = gamma[o] * rsqrtf(rvar[o] + 1e-5f);
            inv[r] = iv; add[r] = beta[o] - rmean[o] * iv;
        }
#pragma unroll
        for (int j = 0; j < 2; j++) {
            int n_g = nbase + j * 16 + col;
            int bq = n_g >> 12, hw = n_g & 4095;
            float* op = out + ((long)bq << 20) + hw;
#pragma unroll
            for (int r = 0; r < 4; r++) {
                float v = acc[i][j][r] * inv[r] + add[r];
                v = fmaxf(v, 0.f);
                op[(long)(ob + r) << 12] = v;
            }
        }
    }
}

// ---------------------------------------------------------------------------
extern "C" void kernel_launch(void* const* d_in, const int* in_sizes, int n_in,
                              void* d_out, int out_size, void* d_ws, size_t ws_size,
                              hipStream_t stream) {
    const float* x     = (const float*)d_in[0];
    const float* woff  = (const float*)d_in[1];
    const float* boff  = (const float*)d_in[2];
    const float* wmod  = (const float*)d_in[3];
    const float* bmod  = (const float*)d_in[4];
    const float* wreg  = (const float*)d_in[5];
    const float* gamma = (const float*)d_in[6];
    const float* beta  = (const float*)d_in[7];
    const float* rmean = (const float*)d_in[8];
    const float* rvar  = (const float*)d_in[9];
    float* out = (float*)d_out;

    char* ws = (char*)d_ws;
    // ws map:
    //   [0x000000, 0x024000)  wph   bf16  144 KB (A hi, koffg)
    //   [0x040000, 0x064000)  wpl   bf16  144 KB (A lo)
    //   [0x080000, 0x23C000)  offf  fp32  1.77 MB
    //   [0x240000, 0x360000)  wregb bf16  1.18 MB ([o][t*256+c] order)
    //   [0x400000, 0x1400000) xt    fp32  16 MB  (channel-last x)
    u16*   wph   = (u16*)(ws);
    u16*   wpl   = (u16*)(ws + 0x40000u);
    float* offf  = (float*)(ws + 0x80000u);
    u16*   wregb = (u16*)(ws + 0x240000u);
    float* xt    = (float*)(ws + 0x400000u);

    kprep<<<288,  256, 0, stream>>>(woff, wmod, wph, wpl);
    kwreg<<<2304, 256, 0, stream>>>(wreg, wregb);
    ktrans<<<dim3(64, 4, 4), 256, 0, stream>>>(x, xt);
    koffg<<<512,  512, 0, stream>>>(xt, wph, wpl, boff, bmod, offf);
    kfused<<<512, 512, 0, stream>>>(xt, offf, wregb, gamma, beta,
                                    rmean, rvar, out);
}

// Round 17
// 168.911 us; speedup vs baseline: 1.0474x; 1.0474x over previous
//
#include <hip/hip_runtime.h>
#include <hip/hip_bf16.h>

typedef unsigned short u16;
typedef unsigned int   u32;
typedef short   bf16x8 __attribute__((ext_vector_type(8)));  // bf16 carried as i16
typedef float   f32x4  __attribute__((ext_vector_type(4)));

__device__ __forceinline__ float bf2f(u16 u) {
    u32 t = ((u32)u) << 16;
    return __builtin_bit_cast(float, t);
}
__device__ __forceinline__ u32 f2bf(float f) {
    u32 u = __builtin_bit_cast(u32, f);
    return (u + 0x7FFFu + ((u >> 16) & 1u)) >> 16;   // RNE
}
// async global->LDS DMA, 16 B per lane (dst = wave-uniform base + lane*16)
__device__ __forceinline__ void load_lds16(const u16* g, u16* l) {
    __builtin_amdgcn_global_load_lds(
        (const __attribute__((address_space(1))) u32*)(const void*)g,
        (__attribute__((address_space(3))) u32*)(void*)l, 16, 0, 0);
}
// Inline-asm loads (saddr form): compiler cannot sink these or auto-wait on
// them -> true async issue, paired with manual vmcnt (rule #18).
// ALL loads 16B-aligned dwordx4 (no alignment hazards).
__device__ __forceinline__ uint4 gload4(const u16* sbase, u32 voff) {
    uint4 r;
    asm volatile("global_load_dwordx4 %0, %1, %2"
                 : "=v"(r) : "v"(voff), "s"(sbase) : "memory");
    return r;
}
__device__ __forceinline__ f32x4 gload4f(const float* sbase, u32 voff) {
    f32x4 r;
    asm volatile("global_load_dwordx4 %0, %1, %2"
                 : "=v"(r) : "v"(voff), "s"(sbase) : "memory");
    return r;
}
#define WAITVM(N) do { asm volatile("s_waitcnt vmcnt(" #N ")" ::: "memory"); \
                       __builtin_amdgcn_sched_barrier(0); } while (0)

// ---------------------------------------------------------------------------
// GLOBAL K-ORDER (both GEMMs): r = t*256 + c  (tap-major).
// XCD swizzle (verified r6): xcd = bid&7 -> 32-row band of one image.
// Channel-last xt[b][pixel][c] (r8). Divergence-aware lane maps (r9/r14).
// T4 raw-barrier pipeline (r12). 2-blocks/CU (r13).
// r16/r17: FUSION — koffg merged into kfused as phase 1. Same-bid blocks
// cover the same 32 pixels, so the offset/mask slice (27ch x 32px = 3.4 KB)
// stays in LDS (offl) instead of a 1.77 MB HBM round trip; one launch gap
// gone; phase LDS footprints alias (72 KB union + offl, 2 blocks/CU).
// Phase 1 = r15 koffg body verbatim (K-split, 19 raw barriers); phase 2 =
// r13 kfused body with tapcomp reading offl. Values bit-identical.
// ---------------------------------------------------------------------------

// Kernel 0a: offset/mask conv weights -> hi/lo bf16 A[32][2304], r = t*256+c
__global__ void kprep(const float* __restrict__ woff, const float* __restrict__ wmod,
                      u16* __restrict__ ah, u16* __restrict__ al) {
    int i = blockIdx.x * 256 + threadIdx.x;      // 288 blocks -> 73728 exact
    if (i >= 32 * 2304) return;
    int oc = i / 2304, r = i - oc * 2304;
    int t = r >> 8, c = r & 255;
    float v = 0.f;
    if (oc < 18)      v = woff[oc * 2304 + c * 9 + t];
    else if (oc < 27) v = wmod[(oc - 18) * 2304 + c * 9 + t];
    u32 hb = f2bf(v);
    u32 lb = f2bf(v - bf2f((u16)hb));
    ah[i] = (u16)hb;
    al[i] = (u16)lb;
}

// Kernel 0b: w_reg f32 -> bf16, layout [o][t*256+c] (matches gather K-order).
__global__ void kwreg(const float* __restrict__ wreg, u16* __restrict__ wregb) {
    int i = blockIdx.x * 256 + threadIdx.x;      // 2304 blocks exact
    int o = i / 2304, r = i - o * 2304;
    int t = r >> 8, c = r & 255;
    wregb[i] = (u16)f2bf(wreg[o * 2304 + c * 9 + t]);
}

// Kernel 0c: transpose x[b][c][p] -> xt[b][p][c]  (channel-last, 16 MB).
__global__ __launch_bounds__(256) void ktrans(const float* __restrict__ x,
                                              float* __restrict__ xt) {
    __shared__ float T[64][65];
    int t = threadIdx.x;
    int pl = t & 63, cr = t >> 6;                // 4 rows per pass
    int p0 = blockIdx.x * 64;                    // pixel tile
    int c0 = blockIdx.y * 64;                    // channel tile
    int b  = blockIdx.z;
    const float* xb  = x  + ((long)b << 20);
    float*       xtb = xt + ((long)b << 20);
#pragma unroll
    for (int i = 0; i < 16; i++) {
        int c = cr + i * 4;
        T[c][pl] = xb[((long)(c0 + c) << 12) + p0 + pl];
    }
    __syncthreads();
#pragma unroll
    for (int i = 0; i < 16; i++) {
        int p = cr + i * 4;
        xtb[(long)(p0 + p) * 256 + c0 + pl] = T[pl][p];
    }
}

// ---------------------------------------------------------------------------
// Kernel 1 (FUSED): offset/mask GEMM -> LDS offl -> deformable sampling +
// GEMM + BN + ReLU. Grid 512 x 512 thr, 2 blocks/CU.
// ---------------------------------------------------------------------------
__global__ __launch_bounds__(512, 4) void kfused(const float* __restrict__ xt,
                                                 const u16* __restrict__ ah_g,
                                                 const u16* __restrict__ al_g,
                                                 const float* __restrict__ boff,
                                                 const float* __restrict__ bmod,
                                                 const u16* __restrict__ wregb,
                                                 const float* __restrict__ gamma,
                                                 const float* __restrict__ beta,
                                                 const float* __restrict__ rmean,
                                                 const float* __restrict__ rvar,
                                                 float* __restrict__ out) {
    __shared__ char  smem[73728];      // 72 KB, aliased by both phases
    __shared__ float offl[27 * 32];    // persistent 3.4 KB: [ch][px]
    int tid = threadIdx.x;
    int lane = tid & 63, wv = tid >> 6;
    int col = lane & 15, quad = lane >> 4;
    // XCD swizzle: 512 blocks, xcd = bid&7 -> (img, band), j -> row/half
    int bid = blockIdx.x;
    int xcd = bid & 7, jj = bid >> 3;            // jj in [0,64)
    int bb  = xcd >> 1;                          // image   (block-uniform)
    int h   = ((xcd & 1) << 5) + (jj >> 1);      // row     (block-uniform)
    int nbase = ((bb << 6) + h) * 64 + (jj & 1) * 32;  // first pixel (32/block)
    int h0 = h, w0 = nbase & 63;
    const float* xtb = xt + ((long)bb << 20);    // image base (SGPR)

    // ============================ PHASE 1 ==================================
    // r15 koffg body: M=32 offset/mask GEMM, K-split across 2 wave-groups.
    {
        u16* AH = (u16*)smem;                    // [4][32*72] each 4608 u16
        u16* AL = AH + 4 * 2304;
        u16* BH = AL + 4 * 2304;
        u16* BL = BH + 4 * 2304;                 // total 73728 B exactly

        int ltid = tid & 255, kg = tid >> 8;     // K-group 0/1
        int mt = wv & 1, nt = (wv >> 1) & 1;     // 2 m-tiles x 2 n-tiles of 16
        int aoc = ltid >> 3, ak0 = (ltid & 7) * 8;   // A staging role
        int chq = lane & 15, pxs = lane >> 4;        // B staging roles
        int px0 = (wv & 3) * 4 + pxs, px1 = px0 + 16;
        int ktb = kg * 18;                       // group's first kt
        u32 avoff0 = (u32)(aoc * 2304 + ak0) * 2;

        f32x4 acc = (f32x4){0.f, 0.f, 0.f, 0.f};
        uint4 pah, pal;
        f32x4 xa, xc;
        bool  vma, vmb;

        auto issue = [&](int kt) {               // 4 asm loads, stay in flight
            int t = kt >> 2, c0 = (kt & 3) << 6, r0 = kt * 64;
            int dy = t / 3 - 1, dx = t % 3 - 1;
            pah = gload4(ah_g, avoff0 + (u32)r0 * 2);
            pal = gload4(al_g, avoff0 + (u32)r0 * 2);
            int hp = h0 + dy;
            bool vh = (unsigned)hp < 64u;
            int hc = min(max(hp, 0), 63);
            u32 cb = (u32)(c0 + chq * 4) << 2;
            int wpa = w0 + px0 + dx;
            vma = vh && ((unsigned)wpa < 64u);
            int wca = min(max(wpa, 0), 63);
            xa = gload4f(xtb, ((u32)(hc * 64 + wca) << 10) + cb);
            int wpb = w0 + px1 + dx;
            vmb = vh && ((unsigned)wpb < 64u);
            int wcb = min(max(wpb, 0), 63);
            xc = gload4f(xtb, ((u32)(hc * 64 + wcb) << 10) + cb);
        };
        auto stores = [&](int buf) {             // after WAITVM(0); buf in {0,1}
            int sb = kg * 2 + buf;
            *(uint4*)&AH[sb * 2304 + aoc * 72 + ak0] = pah;
            *(uint4*)&AL[sb * 2304 + aoc * 72 + ak0] = pal;
            u32 wh[2], wl[2];
#pragma unroll
            for (int i = 0; i < 4; i++) {
                float v = vma ? xa[i] : 0.f;
                u32 hb = f2bf(v);
                u32 lb = f2bf(v - bf2f((u16)hb));
                if (i & 1) { wh[i >> 1] |= hb << 16; wl[i >> 1] |= lb << 16; }
                else       { wh[i >> 1]  = hb;       wl[i >> 1]  = lb; }
            }
            *(uint2*)&BH[sb * 2304 + px0 * 72 + chq * 4] = make_uint2(wh[0], wh[1]);
            *(uint2*)&BL[sb * 2304 + px0 * 72 + chq * 4] = make_uint2(wl[0], wl[1]);
#pragma unroll
            for (int i = 0; i < 4; i++) {
                float v = vmb ? xc[i] : 0.f;
                u32 hb = f2bf(v);
                u32 lb = f2bf(v - bf2f((u16)hb));
                if (i & 1) { wh[i >> 1] |= hb << 16; wl[i >> 1] |= lb << 16; }
                else       { wh[i >> 1]  = hb;       wl[i >> 1]  = lb; }
            }
            *(uint2*)&BH[sb * 2304 + px1 * 72 + chq * 4] = make_uint2(wh[0], wh[1]);
            *(uint2*)&BL[sb * 2304 + px1 * 72 + chq * 4] = make_uint2(wl[0], wl[1]);
        };

        issue(ktb + 0);
        WAITVM(0);
        stores(0);
        issue(ktb + 1);
        asm volatile("s_waitcnt lgkmcnt(0)" ::: "memory");
        __builtin_amdgcn_s_barrier();
        __builtin_amdgcn_sched_barrier(0);

        for (int kt = 0; kt < 18; kt++) {        // group-local kt
            int cur = kt & 1, nxt = kt + 1;
            int sb = kg * 2 + cur;
#pragma unroll
            for (int ks = 0; ks < 2; ks++) {
                int ko = ks * 32 + quad * 8;
                bf16x8 fah = *(const bf16x8*)&AH[sb * 2304 + (mt * 16 + col) * 72 + ko];
                bf16x8 fal = *(const bf16x8*)&AL[sb * 2304 + (mt * 16 + col) * 72 + ko];
                bf16x8 fbh = *(const bf16x8*)&BH[sb * 2304 + (nt * 16 + col) * 72 + ko];
                bf16x8 fbl = *(const bf16x8*)&BL[sb * 2304 + (nt * 16 + col) * 72 + ko];
                acc = __builtin_amdgcn_mfma_f32_16x16x32_bf16(fah, fbh, acc, 0, 0, 0);
                acc = __builtin_amdgcn_mfma_f32_16x16x32_bf16(fah, fbl, acc, 0, 0, 0);
                acc = __builtin_amdgcn_mfma_f32_16x16x32_bf16(fal, fbh, acc, 0, 0, 0);
            }
            if (nxt < 18) {
                WAITVM(0);                       // group batch nxt arrived
                stores(nxt & 1);
                if (nxt + 1 < 18) issue(ktb + nxt + 1);  // flies across barrier
            }
            asm volatile("s_waitcnt lgkmcnt(0)" ::: "memory");
            __builtin_amdgcn_s_barrier();        // RAW barrier: no vmcnt drain
            __builtin_amdgcn_sched_barrier(0);
        }

        // cross-group reduction: kg1 publishes, kg0 adds and writes offl
        float* scratch = (float*)AH;
        if (kg) *(f32x4*)&scratch[ltid * 4] = acc;
        __syncthreads();
        if (kg == 0) {
            f32x4 o = *(const f32x4*)&scratch[ltid * 4];
            acc += o;
            int lpx = nt * 16 + col;             // local pixel 0..31
#pragma unroll
            for (int r = 0; r < 4; r++) {
                int oc = mt * 16 + quad * 4 + r;
                float s = acc[r];
                if (oc < 18) {
                    int ch = 3 * (oc >> 1) + (oc & 1);  // even oc->dy, odd->dx
                    offl[ch * 32 + lpx] = s + boff[oc];
                } else if (oc < 27) {
                    float tt = s + bmod[oc - 18];
                    int ch = 3 * (oc - 18) + 2;
                    offl[ch * 32 + lpx] = 2.f / (1.f + __expf(-tt));
                }
            }
        }
        __syncthreads();                         // offl ready; smem retired
    }

    // ============================ PHASE 2 ==================================
    // r13 kfused body, tapcomp reading offl (LDS) instead of offf (HBM).
    u16* WL = (u16*)smem;                        // [2][256*64] = 65536 B
    u16* SL = WL + 2 * 256 * 64;                 // [2][8*32*8] =  8192 B
    int chq = lane & 15;                         // channel-quad 0..15
    int plo = wv * 4 + (lane >> 4);              // own pixel 0..31
    int wo = wv * 32;                            // wave output tile 32o x 32n

    f32x4 acc[2][2];
#pragma unroll
    for (int i = 0; i < 2; i++)
#pragma unroll
        for (int j = 0; j < 2; j++) acc[i][j] = (f32x4){0.f, 0.f, 0.f, 0.f};

    u32   pb[4];                                 // neighbor record byte offs
    float sw[4];                                 // bilinear*mask weights
    f32x4 g[4];                                  // in-flight 4ch quads

    auto tapcomp = [&](int t) {                  // own pixel's tap state (LDS)
        int w = (nbase + plo) & 63;
        int gy = t / 3, tx = t - 3 * gy;
        float dy = offl[(3 * t + 0) * 32 + plo];
        float dx = offl[(3 * t + 1) * 32 + plo];
        float m  = offl[(3 * t + 2) * 32 + plo];
        float py = (float)(h - 1 + gy) + dy;
        float px = (float)(w - 1 + tx) + dx;
        float y0f = floorf(py), x0f = floorf(px);
        float wy = py - y0f, wx = px - x0f;
        int iy0 = (int)y0f, ix0 = (int)x0f;
        int iy1 = iy0 + 1, ix1 = ix0 + 1;
        bool vy0 = (unsigned)iy0 < 64u, vy1 = (unsigned)iy1 < 64u;
        bool vx0 = (unsigned)ix0 < 64u, vx1 = (unsigned)ix1 < 64u;
        int cy0 = min(max(iy0, 0), 63), cy1 = min(max(iy1, 0), 63);
        int cx0 = min(max(ix0, 0), 63), cx1 = min(max(ix1, 0), 63);
        pb[0] = (u32)(cy0 * 64 + cx0) << 10; pb[1] = (u32)(cy0 * 64 + cx1) << 10;
        pb[2] = (u32)(cy1 * 64 + cx0) << 10; pb[3] = (u32)(cy1 * 64 + cx1) << 10;
        float a = 1.f - wy, bw = 1.f - wx;
        sw[0] = (vy0 && vx0) ? a  * bw * m : 0.f;
        sw[1] = (vy0 && vx1) ? a  * wx * m : 0.f;
        sw[2] = (vy1 && vx0) ? wy * bw * m : 0.f;
        sw[3] = (vy1 && vx1) ? wy * wx * m : 0.f;
    };
    auto gissue = [&](int kt) {                  // 4 dwordx4 (one per neighbor)
        u32 co = ((u32)(kt & 3) << 8) + (u32)chq * 16;
#pragma unroll
        for (int nb = 0; nb < 4; nb++) g[nb] = gload4f(xtb, pb[nb] + co);
    };
    auto dmaA = [&](int kt, int buf) {           // async A staging, 32 KB
#pragma unroll
        for (int i = 0; i < 4; i++) {
            int cidx = tid + i * 512;
            int o = cidx >> 3, qp = cidx & 7;
            int ql = qp ^ (o & 7);               // source-side XOR swizzle
            load_lds16(wregb + (long)o * 2304 + kt * 64 + ql * 8,
                       &WL[buf * 16384 + cidx * 8]);
        }
    };
    auto bwrite = [&](int buf) {                 // combine + pack + 8B write
        f32x4 v = sw[0] * g[0] + sw[1] * g[1] + sw[2] * g[2] + sw[3] * g[3];
        u32 w0 = f2bf(v[0]) | (f2bf(v[1]) << 16);
        u32 w1 = f2bf(v[2]) | (f2bf(v[3]) << 16);
        *(uint2*)&SL[buf * 2048 + ((chq >> 1) * 32 + plo) * 8 + (chq & 1) * 4] =
            make_uint2(w0, w1);
    };

    // prologue: fill buffer 0
    tapcomp(0);
    gissue(0);
    dmaA(0, 0);
    WAITVM(0);
    bwrite(0);
    __syncthreads();

    for (int kt = 0; kt < 36; kt++) {
        int cur = kt & 1, nxt = kt + 1;
        if (nxt < 36) {
            if ((nxt & 3) == 0) tapcomp(nxt >> 2);
            gissue(nxt);                         // 4 oldest outstanding vmem
            dmaA(nxt, nxt & 1);                  // 4 newest (drain at barrier)
        }
#pragma unroll
        for (int ks = 0; ks < 2; ks++) {
            bf16x8 af[2], bfr[2];
#pragma unroll
            for (int i = 0; i < 2; i++) {
                int r = wo + i * 16 + col;
                int ph = (ks * 4 + quad) ^ (r & 7);
                af[i] = *(const bf16x8*)&WL[cur * 16384 + r * 64 + ph * 8];
            }
#pragma unroll
            for (int j = 0; j < 2; j++)
                bfr[j] = *(const bf16x8*)&SL[cur * 2048 + ((ks * 4 + quad) * 32 +
                                             (j * 16 + col)) * 8];
#pragma unroll
            for (int i = 0; i < 2; i++)
#pragma unroll
                for (int j = 0; j < 2; j++)
                    acc[i][j] = __builtin_amdgcn_mfma_f32_16x16x32_bf16(
                        af[i], bfr[j], acc[i][j], 0, 0, 0);
        }
        if (nxt < 36) {
            WAITVM(4);                           // gathers done, DMA may fly
            bwrite(nxt & 1);
        }
        __syncthreads();                         // drains DMA + ds_write; one/kt
    }

    // epilogue: BN + ReLU, D layout: row(o) = quad*4+reg, col(n) = lane&15
#pragma unroll
    for (int i = 0; i < 2; i++) {
        int ob = wo + i * 16 + quad * 4;
        float inv[4], add[4];
#pragma unroll
        for (int r = 0; r < 4; r++) {
            int o = ob + r;
            float iv = gamma[o] * rsqrtf(rvar[o] + 1e-5f);
            inv[r] = iv; add[r] = beta[o] - rmean[o] * iv;
        }
#pragma unroll
        for (int j = 0; j < 2; j++) {
            int n_g = nbase + j * 16 + col;
            int bq = n_g >> 12, hw = n_g & 4095;
            float* op = out + ((long)bq << 20) + hw;
#pragma unroll
            for (int r = 0; r < 4; r++) {
                float v = acc[i][j][r] * inv[r] + add[r];
                v = fmaxf(v, 0.f);
                op[(long)(ob + r) << 12] = v;
            }
        }
    }
}

// ---------------------------------------------------------------------------
extern "C" void kernel_launch(void* const* d_in, const int* in_sizes, int n_in,
                              void* d_out, int out_size, void* d_ws, size_t ws_size,
                              hipStream_t stream) {
    const float* x     = (const float*)d_in[0];
    const float* woff  = (const float*)d_in[1];
    const float* boff  = (const float*)d_in[2];
    const float* wmod  = (const float*)d_in[3];
    const float* bmod  = (const float*)d_in[4];
    const float* wreg  = (const float*)d_in[5];
    const float* gamma = (const float*)d_in[6];
    const float* beta  = (const float*)d_in[7];
    const float* rmean = (const float*)d_in[8];
    const float* rvar  = (const float*)d_in[9];
    float* out = (float*)d_out;

    char* ws = (char*)d_ws;
    // ws map:
    //   [0x000000, 0x024000)  wph   bf16  144 KB (A hi, phase 1)
    //   [0x040000, 0x064000)  wpl   bf16  144 KB (A lo)
    //   [0x240000, 0x360000)  wregb bf16  1.18 MB ([o][t*256+c] order)
    //   [0x400000, 0x1400000) xt    fp32  16 MB  (channel-last x)
    u16*   wph   = (u16*)(ws);
    u16*   wpl   = (u16*)(ws + 0x40000u);
    u16*   wregb = (u16*)(ws + 0x240000u);
    float* xt    = (float*)(ws + 0x400000u);

    kprep<<<288,  256, 0, stream>>>(woff, wmod, wph, wpl);
    kwreg<<<2304, 256, 0, stream>>>(wreg, wregb);
    ktrans<<<dim3(64, 4, 4), 256, 0, stream>>>(x, xt);
    kfused<<<512, 512, 0, stream>>>(xt, wph, wpl, boff, bmod, wregb,
                                    gamma, beta, rmean, rvar, out);
}